// Round 13
// baseline (274.733 us; speedup 1.0000x reference)
//
#include <hip/hip_runtime.h>
#include <hip/hip_bf16.h>

// ---------------------------------------------------------------------------
// RGAT: 2x RGATConv (R=8, H=128) + mean/max pool + MLP head -> scalar
//
// R13 structure (fp8 value path; occupancy-fixed gemmY):
//   CSR build: memset -> k_chist -> k_cscatter -> k_fsort
//   k_wprep (one dispatch, both layers)
//   per layer:
//     k_gemmY<L0>: SINGLE 35KB LDS buffer; A-tile staged once, each wave
//                  hoists its 32 rows into registers (afr[2][4]); buffer then
//                  reused for wqkb (qkv pass) and WT2[r] (r-loop).
//                  r-loop uses SWAPPED mfma(bfv, afr) -> lane holds 4
//                  consecutive h -> 2x cvt_pk_fp8 -> one dword store.
//     k_aggY:  1 wave/node; online-softmax lane-parallel; 4-edge batches
//              (16 lanes x 8B fp8/edge = 1 dwordx2 per 4 edges), register acc.
//   pool (mean+max) -> head
//
// Record packing: rec = src | et<<17 | dlow<<20
// ---------------------------------------------------------------------------

typedef __bf16 bf16x8 __attribute__((ext_vector_type(8)));
typedef __bf16 bf16x4 __attribute__((ext_vector_type(4)));
typedef __bf16 bf16x2 __attribute__((ext_vector_type(2)));
typedef float f32x4 __attribute__((ext_vector_type(4)));
typedef float f32x2 __attribute__((ext_vector_type(2)));

#define CBSH 10
#define CSC_CH 4096

// ----------------------------- CSR build -----------------------------------

__global__ __launch_bounds__(256) void k_chist(const int* __restrict__ dst, int* __restrict__ chist, int E) {
  __shared__ int lh[64];
  int t = threadIdx.x;
  if (t < 64) lh[t] = 0;
  __syncthreads();
  for (int e = blockIdx.x * 256 + t; e < E; e += gridDim.x * 256)
    atomicAdd(&lh[dst[e] >> CBSH], 1);
  __syncthreads();
  if (t < 64 && lh[t]) atomicAdd(&chist[t], lh[t]);
}

__global__ __launch_bounds__(256) void k_cscatter(const int* __restrict__ src, const int* __restrict__ dst,
                                                  const int* __restrict__ et, const int* __restrict__ chist,
                                                  int* __restrict__ ccur0, int* __restrict__ tmp, int E) {
  __shared__ int recbuf[CSC_CH];
  __shared__ int lcnt[64], lbase[64], gbase[64], lcur[64], cb[64];
  int t = threadIdx.x;
  int base = blockIdx.x * CSC_CH;
  int cnt = E - base; if (cnt > CSC_CH) cnt = CSC_CH;
  if (t < 64) { lcnt[t] = 0; cb[t] = chist[t]; }
  __syncthreads();
  int myrec[CSC_CH / 256], mycb[CSC_CH / 256];
  int k = 0;
  for (int i = t; i < cnt; i += 256, ++k) {
    int d = dst[base + i];
    int c = d >> CBSH;
    myrec[k] = src[base + i] | (et[base + i] << 17) | ((d & ((1 << CBSH) - 1)) << 20);
    mycb[k] = c;
    atomicAdd(&lcnt[c], 1);
  }
  __syncthreads();
  if (t == 0) {
    int acc = 0, acc2 = 0;
    for (int c = 0; c < 64; ++c) {
      lbase[c] = acc; lcur[c] = acc; acc += lcnt[c];
      int h = cb[c]; cb[c] = acc2; acc2 += h;
    }
  }
  __syncthreads();
  if (t < 64 && lcnt[t] > 0) gbase[t] = cb[t] + atomicAdd(&ccur0[t], lcnt[t]);
  __syncthreads();
  k = 0;
  for (int i = t; i < cnt; i += 256, ++k) {
    int p = atomicAdd(&lcur[mycb[k]], 1);
    recbuf[p] = myrec[k];
  }
  __syncthreads();
  for (int i = t; i < cnt; i += 256) {
    int lo = 0, hi = 63;
    while (lo < hi) { int mid = (lo + hi + 1) >> 1; if (lbase[mid] <= i) lo = mid; else hi = mid - 1; }
    tmp[gbase[lo] + (i - lbase[lo])] = recbuf[i];
  }
}

__global__ __launch_bounds__(1024) void k_fsort(const int* __restrict__ chist, const int* __restrict__ tmp,
                                                int* __restrict__ recs, int* __restrict__ row_ptr,
                                                int N, int E) {
  __shared__ int sd[1024];
  __shared__ int ncur[1024];
  __shared__ int cbs[65];
  int cb = blockIdx.x, t = threadIdx.x;
  int n0 = cb << CBSH;
  if (t < 64) cbs[t] = chist[t];
  __syncthreads();
  if (t == 0) {
    int acc = 0;
    for (int c = 0; c < 64; ++c) { int h = cbs[c]; cbs[c] = acc; acc += h; }
    cbs[64] = acc;
  }
  sd[t] = 0;
  __syncthreads();
  int begin = cbs[cb], endd = cbs[cb + 1];
  for (int i = begin + t; i < endd; i += 1024)
    atomicAdd(&sd[(tmp[i] >> 20) & 1023], 1);
  __syncthreads();
  int myc = sd[t];
  for (int off = 1; off < 1024; off <<= 1) {
    int xv = 0; if (t >= off) xv = sd[t - off];
    __syncthreads();
    sd[t] += xv;
    __syncthreads();
  }
  int ex = sd[t] - myc;
  int node = n0 + t;
  if (node < N) row_ptr[node] = begin + ex;
  if (node == N - 1) row_ptr[N] = E;
  ncur[t] = begin + ex;
  __syncthreads();
  for (int i = begin + t; i < endd; i += 1024) {
    int rc = tmp[i];
    int p = atomicAdd(&ncur[(rc >> 20) & 1023], 1);
    recs[p] = rc & 0xFFFFF;
  }
}

// ----------------------- merged weight precompute (both layers) --------------

__global__ __launch_bounds__(256) void k_wprep(const float* __restrict__ w0, const float* __restrict__ q0,
                                               const float* __restrict__ k0, const float* __restrict__ w1,
                                               const float* __restrict__ q1, const float* __restrict__ k1,
                                               __bf16* __restrict__ wqkb, __bf16* __restrict__ WT) {
  int layer, bx = blockIdx.x;
  if (bx >= 384) { layer = 1; bx -= 384; } else layer = 0;
  const float* W = layer ? w1 : w0;
  const float* q = layer ? q1 : q0;
  const float* k = layer ? k1 : k0;
  __bf16* wq = wqkb + layer * 2048;
  __bf16* WTl = WT + (size_t)layer * 131072;
  if (bx < 256) {
    int g = bx * 4 + (threadIdx.x >> 6);
    int lane = threadIdx.x & 63;
    const float2* wrow = (const float2*)(W + (size_t)g * 128);
    float2 wv = wrow[lane];
    float2 qv2 = ((const float2*)q)[lane];
    float2 kv2 = ((const float2*)k)[lane];
    float aq = wv.x * qv2.x + wv.y * qv2.y;
    float ak = wv.x * kv2.x + wv.y * kv2.y;
    #pragma unroll
    for (int off = 32; off; off >>= 1) {
      aq += __shfl_xor(aq, off, 64);
      ak += __shfl_xor(ak, off, 64);
    }
    if (lane == 0) { wq[g] = (__bf16)aq; wq[1024 + g] = (__bf16)ak; }
  } else {
    __shared__ float t[32][33];
    int bb = bx - 256;
    int r = bb >> 4;
    int rem = bb & 15;
    int kk0 = (rem & 3) * 32, h0 = (rem >> 2) * 32;
    int tx = threadIdx.x & 31;
    int ty = threadIdx.x >> 5;
    #pragma unroll
    for (int i = 0; i < 4; ++i) {
      int kk = ty + i * 8;
      t[kk][tx] = W[((size_t)r * 128 + kk0 + kk) * 128 + h0 + tx];
    }
    __syncthreads();
    #pragma unroll
    for (int i = 0; i < 4; ++i) {
      int hh = ty + i * 8;
      WTl[(size_t)(h0 + hh) * 1024 + r * 128 + kk0 + tx] = (__bf16)t[tx][hh];
    }
  }
}

// ------------------ fused transform GEMM + qkv (fp8 Y out) -------------------
// Single LDS buffer: stage A -> hoist per-wave A-fragments to registers ->
// reuse buffer for wqkb (qkv pass) then WT2[r] (r loop, swapped MFMA).

#define ASTR 136

template <int L0>
__global__ __launch_bounds__(256) void k_gemmY(const void* __restrict__ xin,
                                               const __bf16* __restrict__ WT2,
                                               const __bf16* __restrict__ wqkb,
                                               unsigned char* __restrict__ Y, float* __restrict__ qkv, int M) {
  __shared__ __bf16 Sbuf[128 * ASTR];
  int bm = blockIdx.x * 128;
  int tid = threadIdx.x;
  int w = tid >> 6, l = tid & 63;
  int srow = tid >> 1;
  int cb8 = (tid & 1) * 8;
  bool valid = (bm + srow) < M;

  // stage A tile (bf16) into Sbuf
  if (L0) {
    const float* gA = (const float*)xin + (size_t)(bm + srow) * 128 + cb8 * 8;
    #pragma unroll
    for (int i = 0; i < 8; ++i) {
      float4 f0 = make_float4(0.f, 0.f, 0.f, 0.f), f1 = f0;
      if (valid) { f0 = *(const float4*)(gA + i * 8); f1 = *(const float4*)(gA + i * 8 + 4); }
      bf16x8 v;
      v[0] = (__bf16)f0.x; v[1] = (__bf16)f0.y; v[2] = (__bf16)f0.z; v[3] = (__bf16)f0.w;
      v[4] = (__bf16)f1.x; v[5] = (__bf16)f1.y; v[6] = (__bf16)f1.z; v[7] = (__bf16)f1.w;
      *(bf16x8*)&Sbuf[srow * ASTR + (cb8 + i) * 8] = v;
    }
  } else {
    const bf16x8* gA = (const bf16x8*)((const __bf16*)xin + (size_t)(bm + srow) * 128);
    #pragma unroll
    for (int i = 0; i < 8; ++i) {
      bf16x8 v = valid ? gA[cb8 + i] : (bf16x8)(__bf16)0.0f;
      *(bf16x8*)&Sbuf[srow * ASTR + (cb8 + i) * 8] = v;
    }
  }
  __syncthreads();

  // hoist this wave's A-fragments into registers: rows w*32+m2*16+(l&15)
  bf16x8 afr[2][4];
  #pragma unroll
  for (int m2 = 0; m2 < 2; ++m2)
    #pragma unroll
    for (int ks = 0; ks < 4; ++ks)
      afr[m2][ks] = *(const bf16x8*)&Sbuf[(w * 32 + m2 * 16 + (l & 15)) * ASTR + ks * 32 + (l >> 4) * 8];
  __syncthreads();

  // stage wqkb (16 rows x 128) and do qkv pass
  {
    int qr = tid >> 4, qc = tid & 15;
    *(bf16x8*)&Sbuf[qr * ASTR + qc * 8] = *(const bf16x8*)(wqkb + (size_t)qr * 128 + qc * 8);
  }
  __syncthreads();
  {
    f32x4 qacc[2];
    qacc[0] = (f32x4)0.f; qacc[1] = (f32x4)0.f;
    #pragma unroll
    for (int ks = 0; ks < 4; ++ks) {
      bf16x8 bq = *(const bf16x8*)&Sbuf[(l & 15) * ASTR + ks * 32 + (l >> 4) * 8];
      #pragma unroll
      for (int m2 = 0; m2 < 2; ++m2)
        qacc[m2] = __builtin_amdgcn_mfma_f32_16x16x32_bf16(afr[m2][ks], bq, qacc[m2], 0, 0, 0);
    }
    #pragma unroll
    for (int m2 = 0; m2 < 2; ++m2)
      #pragma unroll
      for (int j = 0; j < 4; ++j) {
        int row = w * 32 + m2 * 16 + (l >> 4) * 4 + j;
        if (bm + row < M) qkv[(size_t)(bm + row) * 16 + (l & 15)] = qacc[m2][j];
      }
  }

  int arow[2];
  #pragma unroll
  for (int m2 = 0; m2 < 2; ++m2) arow[m2] = w * 32 + m2 * 16 + (l & 15);

  for (int r = 0; r < 8; ++r) {
    __syncthreads();               // everyone done reading Sbuf
    {
      const bf16x8* gB = (const bf16x8*)(WT2 + (size_t)srow * 1024 + r * 128);
      #pragma unroll
      for (int i = 0; i < 8; ++i)
        *(bf16x8*)&Sbuf[srow * ASTR + (cb8 + i) * 8] = gB[cb8 + i];
    }
    __syncthreads();

    f32x4 acc[2][8];
    #pragma unroll
    for (int m2 = 0; m2 < 2; ++m2)
      #pragma unroll
      for (int n2 = 0; n2 < 8; ++n2) acc[m2][n2] = (f32x4)0.f;

    #pragma unroll
    for (int ks = 0; ks < 4; ++ks) {
      bf16x8 bfv[8];
      #pragma unroll
      for (int n2 = 0; n2 < 8; ++n2)
        bfv[n2] = *(const bf16x8*)&Sbuf[(n2 * 16 + (l & 15)) * ASTR + ks * 32 + (l >> 4) * 8];
      // SWAPPED operands: D[h][arow] -> lane holds 4 consecutive h per frag
      #pragma unroll
      for (int m2 = 0; m2 < 2; ++m2)
        #pragma unroll
        for (int n2 = 0; n2 < 8; ++n2)
          acc[m2][n2] = __builtin_amdgcn_mfma_f32_16x16x32_bf16(bfv[n2], afr[m2][ks], acc[m2][n2], 0, 0, 0);
    }

    // store: acc[m2][n2][j] = Y[arow[m2]][h = n2*16 + (l>>4)*4 + j] -> 1 dword
    unsigned char* Yr = Y + ((size_t)r * M + bm) * 128;
    #pragma unroll
    for (int m2 = 0; m2 < 2; ++m2) {
      if (bm + arow[m2] < M) {
        #pragma unroll
        for (int n2 = 0; n2 < 8; ++n2) {
          int pk = __builtin_amdgcn_cvt_pk_fp8_f32(acc[m2][n2][0], acc[m2][n2][1], 0, false);
          pk = __builtin_amdgcn_cvt_pk_fp8_f32(acc[m2][n2][2], acc[m2][n2][3], pk, true);
          *(int*)(Yr + (size_t)arow[m2] * 128 + n2 * 16 + (l >> 4) * 4) = pk;
        }
      }
    }
  }
}

// ------------------- softmax + gather aggregate (fp8 value path) -------------

__global__ __launch_bounds__(256) void k_aggY(const int* __restrict__ row_ptr, const int* __restrict__ recs,
                                              const float* __restrict__ qkv, const unsigned char* __restrict__ Y,
                                              const float* __restrict__ bias, __bf16* __restrict__ hout,
                                              int N) {
  int wv = threadIdx.x >> 6;
  int lane = threadIdx.x & 63;
  int n = blockIdx.x * 4 + wv;
  if (n >= N) return;
  int start = row_ptr[n], end = row_ptr[n + 1];
  const float* qvn = qkv + (size_t)n * 16;
  float denom = 0.f, m_run = -1e30f;
  int sub = lane & 15;
  int grp = lane >> 4;
  float acc[8];
  #pragma unroll
  for (int j = 0; j < 8; ++j) acc[j] = 0.f;

  for (int c0 = start; c0 < end; c0 += 64) {
    int cend = (end < c0 + 64) ? end : (c0 + 64);
    int cnt = cend - c0;
    int p = c0 + lane;
    float a = -1e30f; int rec = 0;
    if (p < cend) {
      rec = recs[p];
      int s = rec & 0x1FFFF, r = (rec >> 17) & 7;
      float t = qvn[r] + qkv[(size_t)s * 16 + 8 + r];
      a = (t >= 0.f) ? t : 0.2f * t;
    }
    float cm = a;
    #pragma unroll
    for (int off = 32; off; off >>= 1) cm = fmaxf(cm, __shfl_xor(cm, off, 64));
    if (cm > m_run) {
      if (m_run > -1e29f) {
        float scale = __expf(m_run - cm);
        denom *= scale;
        #pragma unroll
        for (int j = 0; j < 8; ++j) acc[j] *= scale;
      }
      m_run = cm;
    }
    float wgt = (p < cend) ? __expf(a - m_run) : 0.f;
    float ws = wgt;
    #pragma unroll
    for (int off = 32; off; off >>= 1) ws += __shfl_xor(ws, off, 64);
    denom += ws;
    int wbits = __float_as_int(wgt);

    int nbatch = (cnt + 3) >> 2;
    #pragma unroll 2
    for (int b = 0; b < nbatch; ++b) {
      int idx = grp * 4 + b * 16;
      int rg = __builtin_amdgcn_ds_bpermute(idx, rec);
      int wg = __builtin_amdgcn_ds_bpermute(idx, wbits);
      float fw = __int_as_float(wg);
      int s_ = rg & 0x1FFFF;
      int r_ = (rg >> 17) & 7;
      int2 xv = *(const int2*)(Y + (((size_t)r_ * N + s_) << 7) + sub * 8);
      f32x2 f01 = __builtin_amdgcn_cvt_pk_f32_fp8(xv.x, false);
      f32x2 f23 = __builtin_amdgcn_cvt_pk_f32_fp8(xv.x, true);
      f32x2 f45 = __builtin_amdgcn_cvt_pk_f32_fp8(xv.y, false);
      f32x2 f67 = __builtin_amdgcn_cvt_pk_f32_fp8(xv.y, true);
      acc[0] += fw * f01[0]; acc[1] += fw * f01[1];
      acc[2] += fw * f23[0]; acc[3] += fw * f23[1];
      acc[4] += fw * f45[0]; acc[5] += fw * f45[1];
      acc[6] += fw * f67[0]; acc[7] += fw * f67[1];
    }
  }

  #pragma unroll
  for (int j = 0; j < 8; ++j) {
    acc[j] += __shfl_xor(acc[j], 16, 64);
    acc[j] += __shfl_xor(acc[j], 32, 64);
  }
  float inv = 1.f / (denom + 1e-16f);
  if (grp == 0) {
    float4 b0 = *(const float4*)(bias + sub * 8);
    float4 b1 = *(const float4*)(bias + sub * 8 + 4);
    float bb[8] = {b0.x, b0.y, b0.z, b0.w, b1.x, b1.y, b1.z, b1.w};
    bf16x8 o;
    #pragma unroll
    for (int j = 0; j < 8; ++j) o[j] = (__bf16)fmaxf(acc[j] * inv + bb[j], 0.f);
    *(bf16x8*)(hout + (size_t)n * 128 + sub * 8) = o;
  }
}

// ------------------------------- pool + head ---------------------------------

__global__ __launch_bounds__(256) void k_pool(const __bf16* __restrict__ h, float* __restrict__ gsum,
                                              float* __restrict__ gmax, int N) {
  int c2 = threadIdx.x & 63;
  int grp = threadIdx.x >> 6;
  float s0 = 0.f, s1 = 0.f, m0 = 0.f, m1 = 0.f;
  for (int n = blockIdx.x * 4 + grp; n < N; n += gridDim.x * 4) {
    bf16x2 v = ((const bf16x2*)(h + (size_t)n * 128))[c2];
    float v0 = (float)v.x, v1 = (float)v.y;
    s0 += v0; s1 += v1;
    m0 = fmaxf(m0, v0); m1 = fmaxf(m1, v1);
  }
  __shared__ float ss0[256], ss1[256], sm0[256], sm1[256];
  ss0[threadIdx.x] = s0; ss1[threadIdx.x] = s1;
  sm0[threadIdx.x] = m0; sm1[threadIdx.x] = m1;
  __syncthreads();
  if (grp == 0) {
    #pragma unroll
    for (int g = 1; g < 4; ++g) {
      s0 += ss0[g * 64 + c2]; s1 += ss1[g * 64 + c2];
      m0 = fmaxf(m0, sm0[g * 64 + c2]); m1 = fmaxf(m1, sm1[g * 64 + c2]);
    }
    atomicAdd(&gsum[2 * c2 + 0], s0);
    atomicAdd(&gsum[2 * c2 + 1], s1);
    atomicMax((int*)gmax + 2 * c2 + 0, __float_as_int(m0));
    atomicMax((int*)gmax + 2 * c2 + 1, __float_as_int(m1));
  }
}

__global__ void k_head(const float* __restrict__ gsum, const float* __restrict__ gmax,
                       const float* __restrict__ fc1w, const float* __restrict__ fc1b,
                       const float* __restrict__ fc2w, const float* __restrict__ fc2b,
                       float* __restrict__ out, int N) {
  __shared__ float g[256];
  __shared__ float red[128];
  int t = threadIdx.x;
  if (t < 128) g[t] = tanhf(gsum[t] / (float)N);
  else g[t] = tanhf(gmax[t - 128]);
  __syncthreads();
  float r1 = 0.f;
  if (t < 128) {
    float a = fc1b[t];
    for (int i = 0; i < 256; i++) a += g[i] * fc1w[i * 128 + t];
    r1 = a > 0.f ? a : 0.f;
    red[t] = r1 * fc2w[t];
  }
  __syncthreads();
  for (int s = 64; s > 0; s >>= 1) {
    if (t < s) red[t] += red[t + s];
    __syncthreads();
  }
  if (t == 0) {
    float o = red[0] + fc2b[0];
    out[0] = 1.f / (1.f + __expf(-o));
  }
}

// --------------------------------- launch ------------------------------------

extern "C" void kernel_launch(void* const* d_in, const int* in_sizes, int n_in,
                              void* d_out, int out_size, void* d_ws, size_t ws_size,
                              hipStream_t stream) {
  const float* x    = (const float*)d_in[0];
  const int*   ei   = (const int*)d_in[1];
  const int*   ety  = (const int*)d_in[2];
  const float* w0   = (const float*)d_in[3];
  const float* q0   = (const float*)d_in[4];
  const float* k0   = (const float*)d_in[5];
  const float* b0   = (const float*)d_in[6];
  const float* w1   = (const float*)d_in[7];
  const float* q1   = (const float*)d_in[8];
  const float* k1   = (const float*)d_in[9];
  const float* b1   = (const float*)d_in[10];
  const float* fc1w = (const float*)d_in[11];
  const float* fc1b = (const float*)d_in[12];
  const float* fc2w = (const float*)d_in[13];
  const float* fc2b = (const float*)d_in[14];
  int N = in_sizes[0] / 128;
  int E = in_sizes[2];
  const int* src = ei;
  const int* dst = ei + E;

  char* base = (char*)d_ws;
  size_t off = 0;
  auto alloc = [&](size_t bytes) -> void* {
    off = (off + 255) & ~(size_t)255;
    void* p = base + off;
    off += bytes;
    return p;
  };
  int ncb = (N + (1 << CBSH) - 1) >> CBSH;

  int*    row_ptr = (int*)alloc((size_t)(N + 1) * 4);
  int*    ctrl    = (int*)alloc(384 * 4);
  int*    chist   = ctrl;
  int*    ccur0   = ctrl + 64;
  float*  gpool   = (float*)(ctrl + 128);
  float*  gsum    = gpool;
  float*  gmax    = gpool + 128;
  int*    tmp     = (int*)alloc((size_t)E * 4);
  int*    recs    = (int*)alloc((size_t)E * 4);
  float*  qkv     = (float*)alloc((size_t)N * 16 * 4);
  __bf16* wqkb    = (__bf16*)alloc(2 * 2048 * 2);
  __bf16* h1b     = (__bf16*)alloc((size_t)N * 128 * 2);
  __bf16* h2b     = (__bf16*)alloc((size_t)N * 128 * 2);
  __bf16* WT2     = (__bf16*)alloc((size_t)2 * 131072 * 2);
  unsigned char* Y = (unsigned char*)alloc((size_t)8 * N * 128);

  hipMemsetAsync(ctrl, 0, 384 * 4, stream);
  k_chist<<<256, 256, 0, stream>>>(dst, chist, E);
  k_cscatter<<<(E + CSC_CH - 1) / CSC_CH, 256, 0, stream>>>(src, dst, ety, chist, ccur0, tmp, E);
  k_fsort<<<ncb, 1024, 0, stream>>>(chist, tmp, recs, row_ptr, N, E);

  k_wprep<<<768, 256, 0, stream>>>(w0, q0, k0, w1, q1, k1, wqkb, WT2);

  for (int layer = 0; layer < 2; ++layer) {
    const float* bb   = layer ? b1 : b0;
    __bf16*      hout = layer ? h2b : h1b;
    if (layer == 0)
      k_gemmY<1><<<(N + 127) / 128, 256, 0, stream>>>((const void*)x, WT2, wqkb, Y, qkv, N);
    else
      k_gemmY<0><<<(N + 127) / 128, 256, 0, stream>>>((const void*)h1b, WT2 + 131072, wqkb + 2048, Y, qkv, N);
    k_aggY<<<(N + 3) / 4, 256, 0, stream>>>(row_ptr, recs, qkv, Y, bb, hout, N);
  }

  k_pool<<<256, 256, 0, stream>>>(h2b, gsum, gmax, N);
  k_head<<<1, 256, 0, stream>>>(gsum, gmax, fc1w, fc1b, fc2w, fc2b, (float*)d_out, N);
}

// Round 14
// 257.308 us; speedup vs baseline: 1.0677x; 1.0677x over previous
//
#include <hip/hip_runtime.h>
#include <hip/hip_bf16.h>

// ---------------------------------------------------------------------------
// RGAT: 2x RGATConv (R=8, H=128) + mean/max pool + MLP head -> scalar
//
// R14 structure (fp8 value path; R12 gemmY + relation-split grid):
//   CSR build: memset -> k_chist -> k_cscatter -> k_fsort
//   k_wprep (one dispatch, both layers)
//   per layer:
//     k_gemmY<L0>: grid (tiles, 2); block y owns relations y*4..y*4+3.
//                  A staged once per block (L0 casts f32 in-register);
//                  y==0 blocks also do the qkv pass (A @ wqkb^T).
//                  Y stored fp8 e4m3 (unswapped layout, byte stores).
//     k_aggY:  1 wave/node; online-softmax lane-parallel; 4-edge batches
//              (16 lanes x 8B fp8/edge = 1 dwordx2 per 4 edges), register acc.
//   pool (mean+max) -> head
//
// Record packing: rec = src | et<<17 | dlow<<20
// ---------------------------------------------------------------------------

typedef __bf16 bf16x8 __attribute__((ext_vector_type(8)));
typedef __bf16 bf16x4 __attribute__((ext_vector_type(4)));
typedef __bf16 bf16x2 __attribute__((ext_vector_type(2)));
typedef float f32x4 __attribute__((ext_vector_type(4)));
typedef float f32x2 __attribute__((ext_vector_type(2)));

#define CBSH 10
#define CSC_CH 4096

// ----------------------------- CSR build -----------------------------------

__global__ __launch_bounds__(256) void k_chist(const int* __restrict__ dst, int* __restrict__ chist, int E) {
  __shared__ int lh[64];
  int t = threadIdx.x;
  if (t < 64) lh[t] = 0;
  __syncthreads();
  for (int e = blockIdx.x * 256 + t; e < E; e += gridDim.x * 256)
    atomicAdd(&lh[dst[e] >> CBSH], 1);
  __syncthreads();
  if (t < 64 && lh[t]) atomicAdd(&chist[t], lh[t]);
}

__global__ __launch_bounds__(256) void k_cscatter(const int* __restrict__ src, const int* __restrict__ dst,
                                                  const int* __restrict__ et, const int* __restrict__ chist,
                                                  int* __restrict__ ccur0, int* __restrict__ tmp, int E) {
  __shared__ int recbuf[CSC_CH];
  __shared__ int lcnt[64], lbase[64], gbase[64], lcur[64], cb[64];
  int t = threadIdx.x;
  int base = blockIdx.x * CSC_CH;
  int cnt = E - base; if (cnt > CSC_CH) cnt = CSC_CH;
  if (t < 64) { lcnt[t] = 0; cb[t] = chist[t]; }
  __syncthreads();
  int myrec[CSC_CH / 256], mycb[CSC_CH / 256];
  int k = 0;
  for (int i = t; i < cnt; i += 256, ++k) {
    int d = dst[base + i];
    int c = d >> CBSH;
    myrec[k] = src[base + i] | (et[base + i] << 17) | ((d & ((1 << CBSH) - 1)) << 20);
    mycb[k] = c;
    atomicAdd(&lcnt[c], 1);
  }
  __syncthreads();
  if (t == 0) {
    int acc = 0, acc2 = 0;
    for (int c = 0; c < 64; ++c) {
      lbase[c] = acc; lcur[c] = acc; acc += lcnt[c];
      int h = cb[c]; cb[c] = acc2; acc2 += h;
    }
  }
  __syncthreads();
  if (t < 64 && lcnt[t] > 0) gbase[t] = cb[t] + atomicAdd(&ccur0[t], lcnt[t]);
  __syncthreads();
  k = 0;
  for (int i = t; i < cnt; i += 256, ++k) {
    int p = atomicAdd(&lcur[mycb[k]], 1);
    recbuf[p] = myrec[k];
  }
  __syncthreads();
  for (int i = t; i < cnt; i += 256) {
    int lo = 0, hi = 63;
    while (lo < hi) { int mid = (lo + hi + 1) >> 1; if (lbase[mid] <= i) lo = mid; else hi = mid - 1; }
    tmp[gbase[lo] + (i - lbase[lo])] = recbuf[i];
  }
}

__global__ __launch_bounds__(1024) void k_fsort(const int* __restrict__ chist, const int* __restrict__ tmp,
                                                int* __restrict__ recs, int* __restrict__ row_ptr,
                                                int N, int E) {
  __shared__ int sd[1024];
  __shared__ int ncur[1024];
  __shared__ int cbs[65];
  int cb = blockIdx.x, t = threadIdx.x;
  int n0 = cb << CBSH;
  if (t < 64) cbs[t] = chist[t];
  __syncthreads();
  if (t == 0) {
    int acc = 0;
    for (int c = 0; c < 64; ++c) { int h = cbs[c]; cbs[c] = acc; acc += h; }
    cbs[64] = acc;
  }
  sd[t] = 0;
  __syncthreads();
  int begin = cbs[cb], endd = cbs[cb + 1];
  for (int i = begin + t; i < endd; i += 1024)
    atomicAdd(&sd[(tmp[i] >> 20) & 1023], 1);
  __syncthreads();
  int myc = sd[t];
  for (int off = 1; off < 1024; off <<= 1) {
    int xv = 0; if (t >= off) xv = sd[t - off];
    __syncthreads();
    sd[t] += xv;
    __syncthreads();
  }
  int ex = sd[t] - myc;
  int node = n0 + t;
  if (node < N) row_ptr[node] = begin + ex;
  if (node == N - 1) row_ptr[N] = E;
  ncur[t] = begin + ex;
  __syncthreads();
  for (int i = begin + t; i < endd; i += 1024) {
    int rc = tmp[i];
    int p = atomicAdd(&ncur[(rc >> 20) & 1023], 1);
    recs[p] = rc & 0xFFFFF;
  }
}

// ----------------------- merged weight precompute (both layers) --------------

__global__ __launch_bounds__(256) void k_wprep(const float* __restrict__ w0, const float* __restrict__ q0,
                                               const float* __restrict__ k0, const float* __restrict__ w1,
                                               const float* __restrict__ q1, const float* __restrict__ k1,
                                               __bf16* __restrict__ wqkb, __bf16* __restrict__ WT) {
  int layer, bx = blockIdx.x;
  if (bx >= 384) { layer = 1; bx -= 384; } else layer = 0;
  const float* W = layer ? w1 : w0;
  const float* q = layer ? q1 : q0;
  const float* k = layer ? k1 : k0;
  __bf16* wq = wqkb + layer * 2048;
  __bf16* WTl = WT + (size_t)layer * 131072;
  if (bx < 256) {
    int g = bx * 4 + (threadIdx.x >> 6);
    int lane = threadIdx.x & 63;
    const float2* wrow = (const float2*)(W + (size_t)g * 128);
    float2 wv = wrow[lane];
    float2 qv2 = ((const float2*)q)[lane];
    float2 kv2 = ((const float2*)k)[lane];
    float aq = wv.x * qv2.x + wv.y * qv2.y;
    float ak = wv.x * kv2.x + wv.y * kv2.y;
    #pragma unroll
    for (int off = 32; off; off >>= 1) {
      aq += __shfl_xor(aq, off, 64);
      ak += __shfl_xor(ak, off, 64);
    }
    if (lane == 0) { wq[g] = (__bf16)aq; wq[1024 + g] = (__bf16)ak; }
  } else {
    __shared__ float t[32][33];
    int bb = bx - 256;
    int r = bb >> 4;
    int rem = bb & 15;
    int kk0 = (rem & 3) * 32, h0 = (rem >> 2) * 32;
    int tx = threadIdx.x & 31;
    int ty = threadIdx.x >> 5;
    #pragma unroll
    for (int i = 0; i < 4; ++i) {
      int kk = ty + i * 8;
      t[kk][tx] = W[((size_t)r * 128 + kk0 + kk) * 128 + h0 + tx];
    }
    __syncthreads();
    #pragma unroll
    for (int i = 0; i < 4; ++i) {
      int hh = ty + i * 8;
      WTl[(size_t)(h0 + hh) * 1024 + r * 128 + kk0 + tx] = (__bf16)t[tx][hh];
    }
  }
}

// ------------------ fused transform GEMM + qkv (fp8 Y out) -------------------
// grid (tiles, 2): block y handles relations y*4..y*4+3; y==0 also does qkv.

#define ASTR 136

template <int L0>
__global__ __launch_bounds__(256) void k_gemmY(const void* __restrict__ xin,
                                               const __bf16* __restrict__ WT2,
                                               const __bf16* __restrict__ wqkb,
                                               unsigned char* __restrict__ Y, float* __restrict__ qkv, int M) {
  __shared__ __bf16 As[128 * ASTR];
  __shared__ __bf16 Bs[128 * ASTR];
  int bm = blockIdx.x * 128;
  int rbase = blockIdx.y * 4;
  int tid = threadIdx.x;
  int w = tid >> 6, l = tid & 63;
  int srow = tid >> 1;
  int cb8 = (tid & 1) * 8;
  bool valid = (bm + srow) < M;

  if (L0) {
    const float* gA = (const float*)xin + (size_t)(bm + srow) * 128 + cb8 * 8;
    #pragma unroll
    for (int i = 0; i < 8; ++i) {
      float4 f0 = make_float4(0.f, 0.f, 0.f, 0.f), f1 = f0;
      if (valid) { f0 = *(const float4*)(gA + i * 8); f1 = *(const float4*)(gA + i * 8 + 4); }
      bf16x8 v;
      v[0] = (__bf16)f0.x; v[1] = (__bf16)f0.y; v[2] = (__bf16)f0.z; v[3] = (__bf16)f0.w;
      v[4] = (__bf16)f1.x; v[5] = (__bf16)f1.y; v[6] = (__bf16)f1.z; v[7] = (__bf16)f1.w;
      *(bf16x8*)&As[srow * ASTR + (cb8 + i) * 8] = v;
    }
  } else {
    const bf16x8* gA = (const bf16x8*)((const __bf16*)xin + (size_t)(bm + srow) * 128);
    #pragma unroll
    for (int i = 0; i < 8; ++i) {
      bf16x8 v = valid ? gA[cb8 + i] : (bf16x8)(__bf16)0.0f;
      *(bf16x8*)&As[srow * ASTR + (cb8 + i) * 8] = v;
    }
  }

  if (blockIdx.y == 0) {
    // stage wqkb (16 rows x 128) into Bs and do the qkv pass
    int qr = tid >> 4, qc = tid & 15;
    *(bf16x8*)&Bs[qr * ASTR + qc * 8] = *(const bf16x8*)(wqkb + (size_t)qr * 128 + qc * 8);
    __syncthreads();
    f32x4 qacc[2];
    qacc[0] = (f32x4)0.f; qacc[1] = (f32x4)0.f;
    #pragma unroll
    for (int ks = 0; ks < 4; ++ks) {
      bf16x8 bq = *(const bf16x8*)&Bs[(l & 15) * ASTR + ks * 32 + (l >> 4) * 8];
      #pragma unroll
      for (int m2 = 0; m2 < 2; ++m2) {
        bf16x8 af = *(const bf16x8*)&As[(w * 32 + m2 * 16 + (l & 15)) * ASTR + ks * 32 + (l >> 4) * 8];
        qacc[m2] = __builtin_amdgcn_mfma_f32_16x16x32_bf16(af, bq, qacc[m2], 0, 0, 0);
      }
    }
    #pragma unroll
    for (int m2 = 0; m2 < 2; ++m2)
      #pragma unroll
      for (int j = 0; j < 4; ++j) {
        int row = w * 32 + m2 * 16 + (l >> 4) * 4 + j;
        if (bm + row < M) qkv[(size_t)(bm + row) * 16 + (l & 15)] = qacc[m2][j];
      }
  } else {
    __syncthreads();               // match the A-staging visibility barrier
  }

  for (int rr = 0; rr < 4; ++rr) {
    int r = rbase + rr;
    __syncthreads();
    {
      const bf16x8* gB = (const bf16x8*)(WT2 + (size_t)srow * 1024 + r * 128);
      #pragma unroll
      for (int i = 0; i < 8; ++i)
        *(bf16x8*)&Bs[srow * ASTR + (cb8 + i) * 8] = gB[cb8 + i];
    }
    __syncthreads();

    f32x4 acc[2][8];
    #pragma unroll
    for (int m2 = 0; m2 < 2; ++m2)
      #pragma unroll
      for (int n2 = 0; n2 < 8; ++n2) acc[m2][n2] = (f32x4)0.f;

    #pragma unroll
    for (int ks = 0; ks < 4; ++ks) {
      bf16x8 af[2], bfv[8];
      #pragma unroll
      for (int m2 = 0; m2 < 2; ++m2)
        af[m2] = *(const bf16x8*)&As[(w * 32 + m2 * 16 + (l & 15)) * ASTR + ks * 32 + (l >> 4) * 8];
      #pragma unroll
      for (int n2 = 0; n2 < 8; ++n2)
        bfv[n2] = *(const bf16x8*)&Bs[(n2 * 16 + (l & 15)) * ASTR + ks * 32 + (l >> 4) * 8];
      #pragma unroll
      for (int m2 = 0; m2 < 2; ++m2)
        #pragma unroll
        for (int n2 = 0; n2 < 8; ++n2)
          acc[m2][n2] = __builtin_amdgcn_mfma_f32_16x16x32_bf16(af[m2], bfv[n2], acc[m2][n2], 0, 0, 0);
    }

    // C/D layout: col = lane&15, row = (lane>>4)*4 + reg; store fp8 e4m3
    unsigned char* Yr = Y + ((size_t)r * M + bm) * 128;
    #pragma unroll
    for (int m2 = 0; m2 < 2; ++m2)
      #pragma unroll
      for (int j = 0; j < 4; ++j) {
        int row = w * 32 + m2 * 16 + (l >> 4) * 4 + j;
        if (bm + row < M) {
          #pragma unroll
          for (int n2 = 0; n2 < 8; ++n2) {
            float v = acc[m2][n2][j];
            int pk = __builtin_amdgcn_cvt_pk_fp8_f32(v, v, 0, false);
            Yr[(size_t)row * 128 + n2 * 16 + (l & 15)] = (unsigned char)(pk & 0xFF);
          }
        }
      }
  }
}

// ------------------- softmax + gather aggregate (fp8 value path) -------------

__global__ __launch_bounds__(256) void k_aggY(const int* __restrict__ row_ptr, const int* __restrict__ recs,
                                              const float* __restrict__ qkv, const unsigned char* __restrict__ Y,
                                              const float* __restrict__ bias, __bf16* __restrict__ hout,
                                              int N) {
  int wv = threadIdx.x >> 6;
  int lane = threadIdx.x & 63;
  int n = blockIdx.x * 4 + wv;
  if (n >= N) return;
  int start = row_ptr[n], end = row_ptr[n + 1];
  const float* qvn = qkv + (size_t)n * 16;
  float denom = 0.f, m_run = -1e30f;
  int sub = lane & 15;
  int grp = lane >> 4;
  float acc[8];
  #pragma unroll
  for (int j = 0; j < 8; ++j) acc[j] = 0.f;

  for (int c0 = start; c0 < end; c0 += 64) {
    int cend = (end < c0 + 64) ? end : (c0 + 64);
    int cnt = cend - c0;
    int p = c0 + lane;
    float a = -1e30f; int rec = 0;
    if (p < cend) {
      rec = recs[p];
      int s = rec & 0x1FFFF, r = (rec >> 17) & 7;
      float t = qvn[r] + qkv[(size_t)s * 16 + 8 + r];
      a = (t >= 0.f) ? t : 0.2f * t;
    }
    float cm = a;
    #pragma unroll
    for (int off = 32; off; off >>= 1) cm = fmaxf(cm, __shfl_xor(cm, off, 64));
    if (cm > m_run) {
      if (m_run > -1e29f) {
        float scale = __expf(m_run - cm);
        denom *= scale;
        #pragma unroll
        for (int j = 0; j < 8; ++j) acc[j] *= scale;
      }
      m_run = cm;
    }
    float wgt = (p < cend) ? __expf(a - m_run) : 0.f;
    float ws = wgt;
    #pragma unroll
    for (int off = 32; off; off >>= 1) ws += __shfl_xor(ws, off, 64);
    denom += ws;
    int wbits = __float_as_int(wgt);

    int nbatch = (cnt + 3) >> 2;
    #pragma unroll 2
    for (int b = 0; b < nbatch; ++b) {
      int idx = grp * 4 + b * 16;
      int rg = __builtin_amdgcn_ds_bpermute(idx, rec);
      int wg = __builtin_amdgcn_ds_bpermute(idx, wbits);
      float fw = __int_as_float(wg);
      int s_ = rg & 0x1FFFF;
      int r_ = (rg >> 17) & 7;
      int2 xv = *(const int2*)(Y + (((size_t)r_ * N + s_) << 7) + sub * 8);
      f32x2 f01 = __builtin_amdgcn_cvt_pk_f32_fp8(xv.x, false);
      f32x2 f23 = __builtin_amdgcn_cvt_pk_f32_fp8(xv.x, true);
      f32x2 f45 = __builtin_amdgcn_cvt_pk_f32_fp8(xv.y, false);
      f32x2 f67 = __builtin_amdgcn_cvt_pk_f32_fp8(xv.y, true);
      acc[0] += fw * f01[0]; acc[1] += fw * f01[1];
      acc[2] += fw * f23[0]; acc[3] += fw * f23[1];
      acc[4] += fw * f45[0]; acc[5] += fw * f45[1];
      acc[6] += fw * f67[0]; acc[7] += fw * f67[1];
    }
  }

  #pragma unroll
  for (int j = 0; j < 8; ++j) {
    acc[j] += __shfl_xor(acc[j], 16, 64);
    acc[j] += __shfl_xor(acc[j], 32, 64);
  }
  float inv = 1.f / (denom + 1e-16f);
  if (grp == 0) {
    float4 b0 = *(const float4*)(bias + sub * 8);
    float4 b1 = *(const float4*)(bias + sub * 8 + 4);
    float bb[8] = {b0.x, b0.y, b0.z, b0.w, b1.x, b1.y, b1.z, b1.w};
    bf16x8 o;
    #pragma unroll
    for (int j = 0; j < 8; ++j) o[j] = (__bf16)fmaxf(acc[j] * inv + bb[j], 0.f);
    *(bf16x8*)(hout + (size_t)n * 128 + sub * 8) = o;
  }
}

// ------------------------------- pool + head ---------------------------------

__global__ __launch_bounds__(256) void k_pool(const __bf16* __restrict__ h, float* __restrict__ gsum,
                                              float* __restrict__ gmax, int N) {
  int c2 = threadIdx.x & 63;
  int grp = threadIdx.x >> 6;
  float s0 = 0.f, s1 = 0.f, m0 = 0.f, m1 = 0.f;
  for (int n = blockIdx.x * 4 + grp; n < N; n += gridDim.x * 4) {
    bf16x2 v = ((const bf16x2*)(h + (size_t)n * 128))[c2];
    float v0 = (float)v.x, v1 = (float)v.y;
    s0 += v0; s1 += v1;
    m0 = fmaxf(m0, v0); m1 = fmaxf(m1, v1);
  }
  __shared__ float ss0[256], ss1[256], sm0[256], sm1[256];
  ss0[threadIdx.x] = s0; ss1[threadIdx.x] = s1;
  sm0[threadIdx.x] = m0; sm1[threadIdx.x] = m1;
  __syncthreads();
  if (grp == 0) {
    #pragma unroll
    for (int g = 1; g < 4; ++g) {
      s0 += ss0[g * 64 + c2]; s1 += ss1[g * 64 + c2];
      m0 = fmaxf(m0, sm0[g * 64 + c2]); m1 = fmaxf(m1, sm1[g * 64 + c2]);
    }
    atomicAdd(&gsum[2 * c2 + 0], s0);
    atomicAdd(&gsum[2 * c2 + 1], s1);
    atomicMax((int*)gmax + 2 * c2 + 0, __float_as_int(m0));
    atomicMax((int*)gmax + 2 * c2 + 1, __float_as_int(m1));
  }
}

__global__ void k_head(const float* __restrict__ gsum, const float* __restrict__ gmax,
                       const float* __restrict__ fc1w, const float* __restrict__ fc1b,
                       const float* __restrict__ fc2w, const float* __restrict__ fc2b,
                       float* __restrict__ out, int N) {
  __shared__ float g[256];
  __shared__ float red[128];
  int t = threadIdx.x;
  if (t < 128) g[t] = tanhf(gsum[t] / (float)N);
  else g[t] = tanhf(gmax[t - 128]);
  __syncthreads();
  float r1 = 0.f;
  if (t < 128) {
    float a = fc1b[t];
    for (int i = 0; i < 256; i++) a += g[i] * fc1w[i * 128 + t];
    r1 = a > 0.f ? a : 0.f;
    red[t] = r1 * fc2w[t];
  }
  __syncthreads();
  for (int s = 64; s > 0; s >>= 1) {
    if (t < s) red[t] += red[t + s];
    __syncthreads();
  }
  if (t == 0) {
    float o = red[0] + fc2b[0];
    out[0] = 1.f / (1.f + __expf(-o));
  }
}

// --------------------------------- launch ------------------------------------

extern "C" void kernel_launch(void* const* d_in, const int* in_sizes, int n_in,
                              void* d_out, int out_size, void* d_ws, size_t ws_size,
                              hipStream_t stream) {
  const float* x    = (const float*)d_in[0];
  const int*   ei   = (const int*)d_in[1];
  const int*   ety  = (const int*)d_in[2];
  const float* w0   = (const float*)d_in[3];
  const float* q0   = (const float*)d_in[4];
  const float* k0   = (const float*)d_in[5];
  const float* b0   = (const float*)d_in[6];
  const float* w1   = (const float*)d_in[7];
  const float* q1   = (const float*)d_in[8];
  const float* k1   = (const float*)d_in[9];
  const float* b1   = (const float*)d_in[10];
  const float* fc1w = (const float*)d_in[11];
  const float* fc1b = (const float*)d_in[12];
  const float* fc2w = (const float*)d_in[13];
  const float* fc2b = (const float*)d_in[14];
  int N = in_sizes[0] / 128;
  int E = in_sizes[2];
  const int* src = ei;
  const int* dst = ei + E;

  char* base = (char*)d_ws;
  size_t off = 0;
  auto alloc = [&](size_t bytes) -> void* {
    off = (off + 255) & ~(size_t)255;
    void* p = base + off;
    off += bytes;
    return p;
  };
  int ncb = (N + (1 << CBSH) - 1) >> CBSH;

  int*    row_ptr = (int*)alloc((size_t)(N + 1) * 4);
  int*    ctrl    = (int*)alloc(384 * 4);
  int*    chist   = ctrl;
  int*    ccur0   = ctrl + 64;
  float*  gpool   = (float*)(ctrl + 128);
  float*  gsum    = gpool;
  float*  gmax    = gpool + 128;
  int*    tmp     = (int*)alloc((size_t)E * 4);
  int*    recs    = (int*)alloc((size_t)E * 4);
  float*  qkv     = (float*)alloc((size_t)N * 16 * 4);
  __bf16* wqkb    = (__bf16*)alloc(2 * 2048 * 2);
  __bf16* h1b     = (__bf16*)alloc((size_t)N * 128 * 2);
  __bf16* h2b     = (__bf16*)alloc((size_t)N * 128 * 2);
  __bf16* WT2     = (__bf16*)alloc((size_t)2 * 131072 * 2);
  unsigned char* Y = (unsigned char*)alloc((size_t)8 * N * 128);

  hipMemsetAsync(ctrl, 0, 384 * 4, stream);
  k_chist<<<256, 256, 0, stream>>>(dst, chist, E);
  k_cscatter<<<(E + CSC_CH - 1) / CSC_CH, 256, 0, stream>>>(src, dst, ety, chist, ccur0, tmp, E);
  k_fsort<<<ncb, 1024, 0, stream>>>(chist, tmp, recs, row_ptr, N, E);

  k_wprep<<<768, 256, 0, stream>>>(w0, q0, k0, w1, q1, k1, wqkb, WT2);

  for (int layer = 0; layer < 2; ++layer) {
    const float* bb   = layer ? b1 : b0;
    __bf16*      hout = layer ? h2b : h1b;
    dim3 gg((N + 127) / 128, 2);
    if (layer == 0)
      k_gemmY<1><<<gg, 256, 0, stream>>>((const void*)x, WT2, wqkb, Y, qkv, N);
    else
      k_gemmY<0><<<gg, 256, 0, stream>>>((const void*)h1b, WT2 + 131072, wqkb + 2048, Y, qkv, N);
    k_aggY<<<(N + 3) / 4, 256, 0, stream>>>(row_ptr, recs, qkv, Y, bb, hout, N);
  }

  k_pool<<<256, 256, 0, stream>>>(h2b, gsum, gmax, N);
  k_head<<<1, 256, 0, stream>>>(gsum, gmax, fc1w, fc1b, fc2w, fc2b, (float*)d_out, N);
}

// Round 15
// 223.619 us; speedup vs baseline: 1.2286x; 1.1507x over previous
//
#include <hip/hip_runtime.h>
#include <hip/hip_bf16.h>

// ---------------------------------------------------------------------------
// RGAT: 2x RGATConv (R=8, H=128) + mean/max pool + MLP head -> scalar
//
// R15 structure (R12 gemmY + channel-permuted fp8 Y for vectorized stores):
//   CSR build: memset -> k_chist -> k_cscatter -> k_fsort
//   k_wprep (one dispatch, both layers)
//   per layer:
//     k_gemmY<L0>: R12 double-buffer structure; Y stored fp8 e4m3 in
//                  PERMUTED layout: byte p = (h&15)*8 + (h>>4). The MFMA
//                  fragment's 8 values per node-row are then contiguous ->
//                  4 cvt_pk + 1 dwordx2 store (was 64 cvt + 64 byte stores).
//     k_aggY:  gather/decode unchanged (bytes sub*8+k = channel k*16+sub);
//              only bias load + hout store use the strided channel mapping.
//   pool (mean+max) -> head
//
// Record packing: rec = src | et<<17 | dlow<<20
// ---------------------------------------------------------------------------

typedef __bf16 bf16x8 __attribute__((ext_vector_type(8)));
typedef __bf16 bf16x4 __attribute__((ext_vector_type(4)));
typedef __bf16 bf16x2 __attribute__((ext_vector_type(2)));
typedef float f32x4 __attribute__((ext_vector_type(4)));
typedef float f32x2 __attribute__((ext_vector_type(2)));

#define CBSH 10
#define CSC_CH 4096

// ----------------------------- CSR build -----------------------------------

__global__ __launch_bounds__(256) void k_chist(const int* __restrict__ dst, int* __restrict__ chist, int E) {
  __shared__ int lh[64];
  int t = threadIdx.x;
  if (t < 64) lh[t] = 0;
  __syncthreads();
  for (int e = blockIdx.x * 256 + t; e < E; e += gridDim.x * 256)
    atomicAdd(&lh[dst[e] >> CBSH], 1);
  __syncthreads();
  if (t < 64 && lh[t]) atomicAdd(&chist[t], lh[t]);
}

__global__ __launch_bounds__(256) void k_cscatter(const int* __restrict__ src, const int* __restrict__ dst,
                                                  const int* __restrict__ et, const int* __restrict__ chist,
                                                  int* __restrict__ ccur0, int* __restrict__ tmp, int E) {
  __shared__ int recbuf[CSC_CH];
  __shared__ int lcnt[64], lbase[64], gbase[64], lcur[64], cb[64];
  int t = threadIdx.x;
  int base = blockIdx.x * CSC_CH;
  int cnt = E - base; if (cnt > CSC_CH) cnt = CSC_CH;
  if (t < 64) { lcnt[t] = 0; cb[t] = chist[t]; }
  __syncthreads();
  int myrec[CSC_CH / 256], mycb[CSC_CH / 256];
  int k = 0;
  for (int i = t; i < cnt; i += 256, ++k) {
    int d = dst[base + i];
    int c = d >> CBSH;
    myrec[k] = src[base + i] | (et[base + i] << 17) | ((d & ((1 << CBSH) - 1)) << 20);
    mycb[k] = c;
    atomicAdd(&lcnt[c], 1);
  }
  __syncthreads();
  if (t == 0) {
    int acc = 0, acc2 = 0;
    for (int c = 0; c < 64; ++c) {
      lbase[c] = acc; lcur[c] = acc; acc += lcnt[c];
      int h = cb[c]; cb[c] = acc2; acc2 += h;
    }
  }
  __syncthreads();
  if (t < 64 && lcnt[t] > 0) gbase[t] = cb[t] + atomicAdd(&ccur0[t], lcnt[t]);
  __syncthreads();
  k = 0;
  for (int i = t; i < cnt; i += 256, ++k) {
    int p = atomicAdd(&lcur[mycb[k]], 1);
    recbuf[p] = myrec[k];
  }
  __syncthreads();
  for (int i = t; i < cnt; i += 256) {
    int lo = 0, hi = 63;
    while (lo < hi) { int mid = (lo + hi + 1) >> 1; if (lbase[mid] <= i) lo = mid; else hi = mid - 1; }
    tmp[gbase[lo] + (i - lbase[lo])] = recbuf[i];
  }
}

__global__ __launch_bounds__(1024) void k_fsort(const int* __restrict__ chist, const int* __restrict__ tmp,
                                                int* __restrict__ recs, int* __restrict__ row_ptr,
                                                int N, int E) {
  __shared__ int sd[1024];
  __shared__ int ncur[1024];
  __shared__ int cbs[65];
  int cb = blockIdx.x, t = threadIdx.x;
  int n0 = cb << CBSH;
  if (t < 64) cbs[t] = chist[t];
  __syncthreads();
  if (t == 0) {
    int acc = 0;
    for (int c = 0; c < 64; ++c) { int h = cbs[c]; cbs[c] = acc; acc += h; }
    cbs[64] = acc;
  }
  sd[t] = 0;
  __syncthreads();
  int begin = cbs[cb], endd = cbs[cb + 1];
  for (int i = begin + t; i < endd; i += 1024)
    atomicAdd(&sd[(tmp[i] >> 20) & 1023], 1);
  __syncthreads();
  int myc = sd[t];
  for (int off = 1; off < 1024; off <<= 1) {
    int xv = 0; if (t >= off) xv = sd[t - off];
    __syncthreads();
    sd[t] += xv;
    __syncthreads();
  }
  int ex = sd[t] - myc;
  int node = n0 + t;
  if (node < N) row_ptr[node] = begin + ex;
  if (node == N - 1) row_ptr[N] = E;
  ncur[t] = begin + ex;
  __syncthreads();
  for (int i = begin + t; i < endd; i += 1024) {
    int rc = tmp[i];
    int p = atomicAdd(&ncur[(rc >> 20) & 1023], 1);
    recs[p] = rc & 0xFFFFF;
  }
}

// ----------------------- merged weight precompute (both layers) --------------

__global__ __launch_bounds__(256) void k_wprep(const float* __restrict__ w0, const float* __restrict__ q0,
                                               const float* __restrict__ k0, const float* __restrict__ w1,
                                               const float* __restrict__ q1, const float* __restrict__ k1,
                                               __bf16* __restrict__ wqkb, __bf16* __restrict__ WT) {
  int layer, bx = blockIdx.x;
  if (bx >= 384) { layer = 1; bx -= 384; } else layer = 0;
  const float* W = layer ? w1 : w0;
  const float* q = layer ? q1 : q0;
  const float* k = layer ? k1 : k0;
  __bf16* wq = wqkb + layer * 2048;
  __bf16* WTl = WT + (size_t)layer * 131072;
  if (bx < 256) {
    int g = bx * 4 + (threadIdx.x >> 6);
    int lane = threadIdx.x & 63;
    const float2* wrow = (const float2*)(W + (size_t)g * 128);
    float2 wv = wrow[lane];
    float2 qv2 = ((const float2*)q)[lane];
    float2 kv2 = ((const float2*)k)[lane];
    float aq = wv.x * qv2.x + wv.y * qv2.y;
    float ak = wv.x * kv2.x + wv.y * kv2.y;
    #pragma unroll
    for (int off = 32; off; off >>= 1) {
      aq += __shfl_xor(aq, off, 64);
      ak += __shfl_xor(ak, off, 64);
    }
    if (lane == 0) { wq[g] = (__bf16)aq; wq[1024 + g] = (__bf16)ak; }
  } else {
    __shared__ float t[32][33];
    int bb = bx - 256;
    int r = bb >> 4;
    int rem = bb & 15;
    int kk0 = (rem & 3) * 32, h0 = (rem >> 2) * 32;
    int tx = threadIdx.x & 31;
    int ty = threadIdx.x >> 5;
    #pragma unroll
    for (int i = 0; i < 4; ++i) {
      int kk = ty + i * 8;
      t[kk][tx] = W[((size_t)r * 128 + kk0 + kk) * 128 + h0 + tx];
    }
    __syncthreads();
    #pragma unroll
    for (int i = 0; i < 4; ++i) {
      int hh = ty + i * 8;
      WTl[(size_t)(h0 + hh) * 1024 + r * 128 + kk0 + tx] = (__bf16)t[tx][hh];
    }
  }
}

// ------------------ fused transform GEMM + qkv (fp8 Y out, permuted) ---------

#define ASTR 136

template <int L0>
__global__ __launch_bounds__(256) void k_gemmY(const void* __restrict__ xin,
                                               const __bf16* __restrict__ WT2,
                                               const __bf16* __restrict__ wqkb,
                                               unsigned char* __restrict__ Y, float* __restrict__ qkv, int M) {
  __shared__ __bf16 As[128 * ASTR];
  __shared__ __bf16 Bs[128 * ASTR];
  int bm = blockIdx.x * 128;
  int tid = threadIdx.x;
  int w = tid >> 6, l = tid & 63;
  int srow = tid >> 1;
  int cb8 = (tid & 1) * 8;
  bool valid = (bm + srow) < M;

  if (L0) {
    const float* gA = (const float*)xin + (size_t)(bm + srow) * 128 + cb8 * 8;
    #pragma unroll
    for (int i = 0; i < 8; ++i) {
      float4 f0 = make_float4(0.f, 0.f, 0.f, 0.f), f1 = f0;
      if (valid) { f0 = *(const float4*)(gA + i * 8); f1 = *(const float4*)(gA + i * 8 + 4); }
      bf16x8 v;
      v[0] = (__bf16)f0.x; v[1] = (__bf16)f0.y; v[2] = (__bf16)f0.z; v[3] = (__bf16)f0.w;
      v[4] = (__bf16)f1.x; v[5] = (__bf16)f1.y; v[6] = (__bf16)f1.z; v[7] = (__bf16)f1.w;
      *(bf16x8*)&As[srow * ASTR + (cb8 + i) * 8] = v;
    }
  } else {
    const bf16x8* gA = (const bf16x8*)((const __bf16*)xin + (size_t)(bm + srow) * 128);
    #pragma unroll
    for (int i = 0; i < 8; ++i) {
      bf16x8 v = valid ? gA[cb8 + i] : (bf16x8)(__bf16)0.0f;
      *(bf16x8*)&As[srow * ASTR + (cb8 + i) * 8] = v;
    }
  }
  {
    int qr = tid >> 4, qc = tid & 15;
    *(bf16x8*)&Bs[qr * ASTR + qc * 8] = *(const bf16x8*)(wqkb + (size_t)qr * 128 + qc * 8);
  }
  __syncthreads();

  // pass 0: qkv (16 cols)
  {
    f32x4 qacc[2];
    qacc[0] = (f32x4)0.f; qacc[1] = (f32x4)0.f;
    #pragma unroll
    for (int ks = 0; ks < 4; ++ks) {
      bf16x8 bq = *(const bf16x8*)&Bs[(l & 15) * ASTR + ks * 32 + (l >> 4) * 8];
      #pragma unroll
      for (int m2 = 0; m2 < 2; ++m2) {
        bf16x8 af = *(const bf16x8*)&As[(w * 32 + m2 * 16 + (l & 15)) * ASTR + ks * 32 + (l >> 4) * 8];
        qacc[m2] = __builtin_amdgcn_mfma_f32_16x16x32_bf16(af, bq, qacc[m2], 0, 0, 0);
      }
    }
    #pragma unroll
    for (int m2 = 0; m2 < 2; ++m2)
      #pragma unroll
      for (int j = 0; j < 4; ++j) {
        int row = w * 32 + m2 * 16 + (l >> 4) * 4 + j;
        if (bm + row < M) qkv[(size_t)(bm + row) * 16 + (l & 15)] = qacc[m2][j];
      }
  }

  for (int r = 0; r < 8; ++r) {
    __syncthreads();
    {
      const bf16x8* gB = (const bf16x8*)(WT2 + (size_t)srow * 1024 + r * 128);
      #pragma unroll
      for (int i = 0; i < 8; ++i)
        *(bf16x8*)&Bs[srow * ASTR + (cb8 + i) * 8] = gB[cb8 + i];
    }
    __syncthreads();

    f32x4 acc[2][8];
    #pragma unroll
    for (int m2 = 0; m2 < 2; ++m2)
      #pragma unroll
      for (int n2 = 0; n2 < 8; ++n2) acc[m2][n2] = (f32x4)0.f;

    #pragma unroll
    for (int ks = 0; ks < 4; ++ks) {
      bf16x8 af[2], bfv[8];
      #pragma unroll
      for (int m2 = 0; m2 < 2; ++m2)
        af[m2] = *(const bf16x8*)&As[(w * 32 + m2 * 16 + (l & 15)) * ASTR + ks * 32 + (l >> 4) * 8];
      #pragma unroll
      for (int n2 = 0; n2 < 8; ++n2)
        bfv[n2] = *(const bf16x8*)&Bs[(n2 * 16 + (l & 15)) * ASTR + ks * 32 + (l >> 4) * 8];
      #pragma unroll
      for (int m2 = 0; m2 < 2; ++m2)
        #pragma unroll
        for (int n2 = 0; n2 < 8; ++n2)
          acc[m2][n2] = __builtin_amdgcn_mfma_f32_16x16x32_bf16(af[m2], bfv[n2], acc[m2][n2], 0, 0, 0);
    }

    // Permuted fp8 store: thread's 8 values per node-row (channels n2*16+(l&15))
    // land at bytes (l&15)*8 + n2 -> one dwordx2 per row.
    unsigned char* Yr = Y + ((size_t)r * M + bm) * 128;
    #pragma unroll
    for (int m2 = 0; m2 < 2; ++m2)
      #pragma unroll
      for (int j = 0; j < 4; ++j) {
        int row = w * 32 + m2 * 16 + (l >> 4) * 4 + j;
        if (bm + row < M) {
          int pk0 = __builtin_amdgcn_cvt_pk_fp8_f32(acc[m2][0][j], acc[m2][1][j], 0, false);
          pk0 = __builtin_amdgcn_cvt_pk_fp8_f32(acc[m2][2][j], acc[m2][3][j], pk0, true);
          int pk1 = __builtin_amdgcn_cvt_pk_fp8_f32(acc[m2][4][j], acc[m2][5][j], 0, false);
          pk1 = __builtin_amdgcn_cvt_pk_fp8_f32(acc[m2][6][j], acc[m2][7][j], pk1, true);
          *(int2*)(Yr + (size_t)row * 128 + (l & 15) * 8) = make_int2(pk0, pk1);
        }
      }
  }
}

// ------------------- softmax + gather aggregate (fp8 value path) -------------
// Y bytes sub*8+k hold channel k*16+sub -> acc[k] owns channel k*16+sub.

__global__ __launch_bounds__(256) void k_aggY(const int* __restrict__ row_ptr, const int* __restrict__ recs,
                                              const float* __restrict__ qkv, const unsigned char* __restrict__ Y,
                                              const float* __restrict__ bias, __bf16* __restrict__ hout,
                                              int N) {
  int wv = threadIdx.x >> 6;
  int lane = threadIdx.x & 63;
  int n = blockIdx.x * 4 + wv;
  if (n >= N) return;
  int start = row_ptr[n], end = row_ptr[n + 1];
  const float* qvn = qkv + (size_t)n * 16;
  float denom = 0.f, m_run = -1e30f;
  int sub = lane & 15;
  int grp = lane >> 4;
  float acc[8];
  #pragma unroll
  for (int j = 0; j < 8; ++j) acc[j] = 0.f;

  for (int c0 = start; c0 < end; c0 += 64) {
    int cend = (end < c0 + 64) ? end : (c0 + 64);
    int cnt = cend - c0;
    int p = c0 + lane;
    float a = -1e30f; int rec = 0;
    if (p < cend) {
      rec = recs[p];
      int s = rec & 0x1FFFF, r = (rec >> 17) & 7;
      float t = qvn[r] + qkv[(size_t)s * 16 + 8 + r];
      a = (t >= 0.f) ? t : 0.2f * t;
    }
    float cm = a;
    #pragma unroll
    for (int off = 32; off; off >>= 1) cm = fmaxf(cm, __shfl_xor(cm, off, 64));
    if (cm > m_run) {
      if (m_run > -1e29f) {
        float scale = __expf(m_run - cm);
        denom *= scale;
        #pragma unroll
        for (int j = 0; j < 8; ++j) acc[j] *= scale;
      }
      m_run = cm;
    }
    float wgt = (p < cend) ? __expf(a - m_run) : 0.f;
    float ws = wgt;
    #pragma unroll
    for (int off = 32; off; off >>= 1) ws += __shfl_xor(ws, off, 64);
    denom += ws;
    int wbits = __float_as_int(wgt);

    int nbatch = (cnt + 3) >> 2;
    #pragma unroll 2
    for (int b = 0; b < nbatch; ++b) {
      int idx = grp * 4 + b * 16;
      int rg = __builtin_amdgcn_ds_bpermute(idx, rec);
      int wg = __builtin_amdgcn_ds_bpermute(idx, wbits);
      float fw = __int_as_float(wg);
      int s_ = rg & 0x1FFFF;
      int r_ = (rg >> 17) & 7;
      int2 xv = *(const int2*)(Y + (((size_t)r_ * N + s_) << 7) + sub * 8);
      f32x2 f01 = __builtin_amdgcn_cvt_pk_f32_fp8(xv.x, false);
      f32x2 f23 = __builtin_amdgcn_cvt_pk_f32_fp8(xv.x, true);
      f32x2 f45 = __builtin_amdgcn_cvt_pk_f32_fp8(xv.y, false);
      f32x2 f67 = __builtin_amdgcn_cvt_pk_f32_fp8(xv.y, true);
      acc[0] += fw * f01[0]; acc[1] += fw * f01[1];
      acc[2] += fw * f23[0]; acc[3] += fw * f23[1];
      acc[4] += fw * f45[0]; acc[5] += fw * f45[1];
      acc[6] += fw * f67[0]; acc[7] += fw * f67[1];
    }
  }

  #pragma unroll
  for (int j = 0; j < 8; ++j) {
    acc[j] += __shfl_xor(acc[j], 16, 64);
    acc[j] += __shfl_xor(acc[j], 32, 64);
  }
  float inv = 1.f / (denom + 1e-16f);
  if (grp == 0) {
    // acc[j] is channel j*16+sub
    #pragma unroll
    for (int j = 0; j < 8; ++j) {
      float v = fmaxf(acc[j] * inv + bias[j * 16 + sub], 0.f);
      hout[(size_t)n * 128 + j * 16 + sub] = (__bf16)v;
    }
  }
}

// ------------------------------- pool + head ---------------------------------

__global__ __launch_bounds__(256) void k_pool(const __bf16* __restrict__ h, float* __restrict__ gsum,
                                              float* __restrict__ gmax, int N) {
  int c2 = threadIdx.x & 63;
  int grp = threadIdx.x >> 6;
  float s0 = 0.f, s1 = 0.f, m0 = 0.f, m1 = 0.f;
  for (int n = blockIdx.x * 4 + grp; n < N; n += gridDim.x * 4) {
    bf16x2 v = ((const bf16x2*)(h + (size_t)n * 128))[c2];
    float v0 = (float)v.x, v1 = (float)v.y;
    s0 += v0; s1 += v1;
    m0 = fmaxf(m0, v0); m1 = fmaxf(m1, v1);
  }
  __shared__ float ss0[256], ss1[256], sm0[256], sm1[256];
  ss0[threadIdx.x] = s0; ss1[threadIdx.x] = s1;
  sm0[threadIdx.x] = m0; sm1[threadIdx.x] = m1;
  __syncthreads();
  if (grp == 0) {
    #pragma unroll
    for (int g = 1; g < 4; ++g) {
      s0 += ss0[g * 64 + c2]; s1 += ss1[g * 64 + c2];
      m0 = fmaxf(m0, sm0[g * 64 + c2]); m1 = fmaxf(m1, sm1[g * 64 + c2]);
    }
    atomicAdd(&gsum[2 * c2 + 0], s0);
    atomicAdd(&gsum[2 * c2 + 1], s1);
    atomicMax((int*)gmax + 2 * c2 + 0, __float_as_int(m0));
    atomicMax((int*)gmax + 2 * c2 + 1, __float_as_int(m1));
  }
}

__global__ void k_head(const float* __restrict__ gsum, const float* __restrict__ gmax,
                       const float* __restrict__ fc1w, const float* __restrict__ fc1b,
                       const float* __restrict__ fc2w, const float* __restrict__ fc2b,
                       float* __restrict__ out, int N) {
  __shared__ float g[256];
  __shared__ float red[128];
  int t = threadIdx.x;
  if (t < 128) g[t] = tanhf(gsum[t] / (float)N);
  else g[t] = tanhf(gmax[t - 128]);
  __syncthreads();
  float r1 = 0.f;
  if (t < 128) {
    float a = fc1b[t];
    for (int i = 0; i < 256; i++) a += g[i] * fc1w[i * 128 + t];
    r1 = a > 0.f ? a : 0.f;
    red[t] = r1 * fc2w[t];
  }
  __syncthreads();
  for (int s = 64; s > 0; s >>= 1) {
    if (t < s) red[t] += red[t + s];
    __syncthreads();
  }
  if (t == 0) {
    float o = red[0] + fc2b[0];
    out[0] = 1.f / (1.f + __expf(-o));
  }
}

// --------------------------------- launch ------------------------------------

extern "C" void kernel_launch(void* const* d_in, const int* in_sizes, int n_in,
                              void* d_out, int out_size, void* d_ws, size_t ws_size,
                              hipStream_t stream) {
  const float* x    = (const float*)d_in[0];
  const int*   ei   = (const int*)d_in[1];
  const int*   ety  = (const int*)d_in[2];
  const float* w0   = (const float*)d_in[3];
  const float* q0   = (const float*)d_in[4];
  const float* k0   = (const float*)d_in[5];
  const float* b0   = (const float*)d_in[6];
  const float* w1   = (const float*)d_in[7];
  const float* q1   = (const float*)d_in[8];
  const float* k1   = (const float*)d_in[9];
  const float* b1   = (const float*)d_in[10];
  const float* fc1w = (const float*)d_in[11];
  const float* fc1b = (const float*)d_in[12];
  const float* fc2w = (const float*)d_in[13];
  const float* fc2b = (const float*)d_in[14];
  int N = in_sizes[0] / 128;
  int E = in_sizes[2];
  const int* src = ei;
  const int* dst = ei + E;

  char* base = (char*)d_ws;
  size_t off = 0;
  auto alloc = [&](size_t bytes) -> void* {
    off = (off + 255) & ~(size_t)255;
    void* p = base + off;
    off += bytes;
    return p;
  };
  int ncb = (N + (1 << CBSH) - 1) >> CBSH;

  int*    row_ptr = (int*)alloc((size_t)(N + 1) * 4);
  int*    ctrl    = (int*)alloc(384 * 4);
  int*    chist   = ctrl;
  int*    ccur0   = ctrl + 64;
  float*  gpool   = (float*)(ctrl + 128);
  float*  gsum    = gpool;
  float*  gmax    = gpool + 128;
  int*    tmp     = (int*)alloc((size_t)E * 4);
  int*    recs    = (int*)alloc((size_t)E * 4);
  float*  qkv     = (float*)alloc((size_t)N * 16 * 4);
  __bf16* wqkb    = (__bf16*)alloc(2 * 2048 * 2);
  __bf16* h1b     = (__bf16*)alloc((size_t)N * 128 * 2);
  __bf16* h2b     = (__bf16*)alloc((size_t)N * 128 * 2);
  __bf16* WT2     = (__bf16*)alloc((size_t)2 * 131072 * 2);
  unsigned char* Y = (unsigned char*)alloc((size_t)8 * N * 128);

  hipMemsetAsync(ctrl, 0, 384 * 4, stream);
  k_chist<<<256, 256, 0, stream>>>(dst, chist, E);
  k_cscatter<<<(E + CSC_CH - 1) / CSC_CH, 256, 0, stream>>>(src, dst, ety, chist, ccur0, tmp, E);
  k_fsort<<<ncb, 1024, 0, stream>>>(chist, tmp, recs, row_ptr, N, E);

  k_wprep<<<768, 256, 0, stream>>>(w0, q0, k0, w1, q1, k1, wqkb, WT2);

  for (int layer = 0; layer < 2; ++layer) {
    const float* bb   = layer ? b1 : b0;
    __bf16*      hout = layer ? h2b : h1b;
    if (layer == 0)
      k_gemmY<1><<<(N + 127) / 128, 256, 0, stream>>>((const void*)x, WT2, wqkb, Y, qkv, N);
    else
      k_gemmY<0><<<(N + 127) / 128, 256, 0, stream>>>((const void*)h1b, WT2 + 131072, wqkb + 2048, Y, qkv, N);
    k_aggY<<<(N + 3) / 4, 256, 0, stream>>>(row_ptr, recs, qkv, Y, bb, hout, N);
  }

  k_pool<<<256, 256, 0, stream>>>(h2b, gsum, gmax, N);
  k_head<<<1, 256, 0, stream>>>(gsum, gmax, fc1w, fc1b, fc2w, fc2b, (float*)d_out, N);
}

// Round 16
// 223.000 us; speedup vs baseline: 1.2320x; 1.0028x over previous
//
#include <hip/hip_runtime.h>
#include <hip/hip_bf16.h>

// ---------------------------------------------------------------------------
// RGAT: 2x RGATConv (R=8, H=128) + mean/max pool + MLP head -> scalar
//
// R16 structure (R15 + k_zero kernel instead of pathological tiny memset):
//   k_zero (1 block) zeroes ctrl[384] (chist+ccur0+gsum+gmax)
//   CSR build: k_chist -> k_cscatter (in-block scan) -> k_fsort
//   k_wprep (one dispatch, both layers)
//   per layer:
//     k_gemmY<L0>: R12 double-buffer; Y fp8 e4m3 PERMUTED layout
//                  (byte p = (h&15)*8 + (h>>4)) -> 4 cvt_pk + dwordx2 store.
//     k_aggY:  1 wave/node; online-softmax lane-parallel; 4-edge batches
//              (16 lanes x 8B fp8/edge), register acc + group shfl reduce.
//   pool (mean+max) -> head
//
// Record packing: rec = src | et<<17 | dlow<<20
// ---------------------------------------------------------------------------

typedef __bf16 bf16x8 __attribute__((ext_vector_type(8)));
typedef __bf16 bf16x4 __attribute__((ext_vector_type(4)));
typedef __bf16 bf16x2 __attribute__((ext_vector_type(2)));
typedef float f32x4 __attribute__((ext_vector_type(4)));
typedef float f32x2 __attribute__((ext_vector_type(2)));

#define CBSH 10
#define CSC_CH 4096

// ------------------------------- utility ------------------------------------

__global__ void k_zero(int* __restrict__ p, int n) {
  int i = threadIdx.x;
  if (i < n) p[i] = 0;
}

// ----------------------------- CSR build -----------------------------------

__global__ __launch_bounds__(256) void k_chist(const int* __restrict__ dst, int* __restrict__ chist, int E) {
  __shared__ int lh[64];
  int t = threadIdx.x;
  if (t < 64) lh[t] = 0;
  __syncthreads();
  for (int e = blockIdx.x * 256 + t; e < E; e += gridDim.x * 256)
    atomicAdd(&lh[dst[e] >> CBSH], 1);
  __syncthreads();
  if (t < 64 && lh[t]) atomicAdd(&chist[t], lh[t]);
}

__global__ __launch_bounds__(256) void k_cscatter(const int* __restrict__ src, const int* __restrict__ dst,
                                                  const int* __restrict__ et, const int* __restrict__ chist,
                                                  int* __restrict__ ccur0, int* __restrict__ tmp, int E) {
  __shared__ int recbuf[CSC_CH];
  __shared__ int lcnt[64], lbase[64], gbase[64], lcur[64], cb[64];
  int t = threadIdx.x;
  int base = blockIdx.x * CSC_CH;
  int cnt = E - base; if (cnt > CSC_CH) cnt = CSC_CH;
  if (t < 64) { lcnt[t] = 0; cb[t] = chist[t]; }
  __syncthreads();
  int myrec[CSC_CH / 256], mycb[CSC_CH / 256];
  int k = 0;
  for (int i = t; i < cnt; i += 256, ++k) {
    int d = dst[base + i];
    int c = d >> CBSH;
    myrec[k] = src[base + i] | (et[base + i] << 17) | ((d & ((1 << CBSH) - 1)) << 20);
    mycb[k] = c;
    atomicAdd(&lcnt[c], 1);
  }
  __syncthreads();
  if (t == 0) {
    int acc = 0, acc2 = 0;
    for (int c = 0; c < 64; ++c) {
      lbase[c] = acc; lcur[c] = acc; acc += lcnt[c];
      int h = cb[c]; cb[c] = acc2; acc2 += h;
    }
  }
  __syncthreads();
  if (t < 64 && lcnt[t] > 0) gbase[t] = cb[t] + atomicAdd(&ccur0[t], lcnt[t]);
  __syncthreads();
  k = 0;
  for (int i = t; i < cnt; i += 256, ++k) {
    int p = atomicAdd(&lcur[mycb[k]], 1);
    recbuf[p] = myrec[k];
  }
  __syncthreads();
  for (int i = t; i < cnt; i += 256) {
    int lo = 0, hi = 63;
    while (lo < hi) { int mid = (lo + hi + 1) >> 1; if (lbase[mid] <= i) lo = mid; else hi = mid - 1; }
    tmp[gbase[lo] + (i - lbase[lo])] = recbuf[i];
  }
}

__global__ __launch_bounds__(1024) void k_fsort(const int* __restrict__ chist, const int* __restrict__ tmp,
                                                int* __restrict__ recs, int* __restrict__ row_ptr,
                                                int N, int E) {
  __shared__ int sd[1024];
  __shared__ int ncur[1024];
  __shared__ int cbs[65];
  int cb = blockIdx.x, t = threadIdx.x;
  int n0 = cb << CBSH;
  if (t < 64) cbs[t] = chist[t];
  __syncthreads();
  if (t == 0) {
    int acc = 0;
    for (int c = 0; c < 64; ++c) { int h = cbs[c]; cbs[c] = acc; acc += h; }
    cbs[64] = acc;
  }
  sd[t] = 0;
  __syncthreads();
  int begin = cbs[cb], endd = cbs[cb + 1];
  for (int i = begin + t; i < endd; i += 1024)
    atomicAdd(&sd[(tmp[i] >> 20) & 1023], 1);
  __syncthreads();
  int myc = sd[t];
  for (int off = 1; off < 1024; off <<= 1) {
    int xv = 0; if (t >= off) xv = sd[t - off];
    __syncthreads();
    sd[t] += xv;
    __syncthreads();
  }
  int ex = sd[t] - myc;
  int node = n0 + t;
  if (node < N) row_ptr[node] = begin + ex;
  if (node == N - 1) row_ptr[N] = E;
  ncur[t] = begin + ex;
  __syncthreads();
  for (int i = begin + t; i < endd; i += 1024) {
    int rc = tmp[i];
    int p = atomicAdd(&ncur[(rc >> 20) & 1023], 1);
    recs[p] = rc & 0xFFFFF;
  }
}

// ----------------------- merged weight precompute (both layers) --------------

__global__ __launch_bounds__(256) void k_wprep(const float* __restrict__ w0, const float* __restrict__ q0,
                                               const float* __restrict__ k0, const float* __restrict__ w1,
                                               const float* __restrict__ q1, const float* __restrict__ k1,
                                               __bf16* __restrict__ wqkb, __bf16* __restrict__ WT) {
  int layer, bx = blockIdx.x;
  if (bx >= 384) { layer = 1; bx -= 384; } else layer = 0;
  const float* W = layer ? w1 : w0;
  const float* q = layer ? q1 : q0;
  const float* k = layer ? k1 : k0;
  __bf16* wq = wqkb + layer * 2048;
  __bf16* WTl = WT + (size_t)layer * 131072;
  if (bx < 256) {
    int g = bx * 4 + (threadIdx.x >> 6);
    int lane = threadIdx.x & 63;
    const float2* wrow = (const float2*)(W + (size_t)g * 128);
    float2 wv = wrow[lane];
    float2 qv2 = ((const float2*)q)[lane];
    float2 kv2 = ((const float2*)k)[lane];
    float aq = wv.x * qv2.x + wv.y * qv2.y;
    float ak = wv.x * kv2.x + wv.y * kv2.y;
    #pragma unroll
    for (int off = 32; off; off >>= 1) {
      aq += __shfl_xor(aq, off, 64);
      ak += __shfl_xor(ak, off, 64);
    }
    if (lane == 0) { wq[g] = (__bf16)aq; wq[1024 + g] = (__bf16)ak; }
  } else {
    __shared__ float t[32][33];
    int bb = bx - 256;
    int r = bb >> 4;
    int rem = bb & 15;
    int kk0 = (rem & 3) * 32, h0 = (rem >> 2) * 32;
    int tx = threadIdx.x & 31;
    int ty = threadIdx.x >> 5;
    #pragma unroll
    for (int i = 0; i < 4; ++i) {
      int kk = ty + i * 8;
      t[kk][tx] = W[((size_t)r * 128 + kk0 + kk) * 128 + h0 + tx];
    }
    __syncthreads();
    #pragma unroll
    for (int i = 0; i < 4; ++i) {
      int hh = ty + i * 8;
      WTl[(size_t)(h0 + hh) * 1024 + r * 128 + kk0 + tx] = (__bf16)t[tx][hh];
    }
  }
}

// ------------------ fused transform GEMM + qkv (fp8 Y out, permuted) ---------

#define ASTR 136

template <int L0>
__global__ __launch_bounds__(256) void k_gemmY(const void* __restrict__ xin,
                                               const __bf16* __restrict__ WT2,
                                               const __bf16* __restrict__ wqkb,
                                               unsigned char* __restrict__ Y, float* __restrict__ qkv, int M) {
  __shared__ __bf16 As[128 * ASTR];
  __shared__ __bf16 Bs[128 * ASTR];
  int bm = blockIdx.x * 128;
  int tid = threadIdx.x;
  int w = tid >> 6, l = tid & 63;
  int srow = tid >> 1;
  int cb8 = (tid & 1) * 8;
  bool valid = (bm + srow) < M;

  if (L0) {
    const float* gA = (const float*)xin + (size_t)(bm + srow) * 128 + cb8 * 8;
    #pragma unroll
    for (int i = 0; i < 8; ++i) {
      float4 f0 = make_float4(0.f, 0.f, 0.f, 0.f), f1 = f0;
      if (valid) { f0 = *(const float4*)(gA + i * 8); f1 = *(const float4*)(gA + i * 8 + 4); }
      bf16x8 v;
      v[0] = (__bf16)f0.x; v[1] = (__bf16)f0.y; v[2] = (__bf16)f0.z; v[3] = (__bf16)f0.w;
      v[4] = (__bf16)f1.x; v[5] = (__bf16)f1.y; v[6] = (__bf16)f1.z; v[7] = (__bf16)f1.w;
      *(bf16x8*)&As[srow * ASTR + (cb8 + i) * 8] = v;
    }
  } else {
    const bf16x8* gA = (const bf16x8*)((const __bf16*)xin + (size_t)(bm + srow) * 128);
    #pragma unroll
    for (int i = 0; i < 8; ++i) {
      bf16x8 v = valid ? gA[cb8 + i] : (bf16x8)(__bf16)0.0f;
      *(bf16x8*)&As[srow * ASTR + (cb8 + i) * 8] = v;
    }
  }
  {
    int qr = tid >> 4, qc = tid & 15;
    *(bf16x8*)&Bs[qr * ASTR + qc * 8] = *(const bf16x8*)(wqkb + (size_t)qr * 128 + qc * 8);
  }
  __syncthreads();

  // pass 0: qkv (16 cols)
  {
    f32x4 qacc[2];
    qacc[0] = (f32x4)0.f; qacc[1] = (f32x4)0.f;
    #pragma unroll
    for (int ks = 0; ks < 4; ++ks) {
      bf16x8 bq = *(const bf16x8*)&Bs[(l & 15) * ASTR + ks * 32 + (l >> 4) * 8];
      #pragma unroll
      for (int m2 = 0; m2 < 2; ++m2) {
        bf16x8 af = *(const bf16x8*)&As[(w * 32 + m2 * 16 + (l & 15)) * ASTR + ks * 32 + (l >> 4) * 8];
        qacc[m2] = __builtin_amdgcn_mfma_f32_16x16x32_bf16(af, bq, qacc[m2], 0, 0, 0);
      }
    }
    #pragma unroll
    for (int m2 = 0; m2 < 2; ++m2)
      #pragma unroll
      for (int j = 0; j < 4; ++j) {
        int row = w * 32 + m2 * 16 + (l >> 4) * 4 + j;
        if (bm + row < M) qkv[(size_t)(bm + row) * 16 + (l & 15)] = qacc[m2][j];
      }
  }

  for (int r = 0; r < 8; ++r) {
    __syncthreads();
    {
      const bf16x8* gB = (const bf16x8*)(WT2 + (size_t)srow * 1024 + r * 128);
      #pragma unroll
      for (int i = 0; i < 8; ++i)
        *(bf16x8*)&Bs[srow * ASTR + (cb8 + i) * 8] = gB[cb8 + i];
    }
    __syncthreads();

    f32x4 acc[2][8];
    #pragma unroll
    for (int m2 = 0; m2 < 2; ++m2)
      #pragma unroll
      for (int n2 = 0; n2 < 8; ++n2) acc[m2][n2] = (f32x4)0.f;

    #pragma unroll
    for (int ks = 0; ks < 4; ++ks) {
      bf16x8 af[2], bfv[8];
      #pragma unroll
      for (int m2 = 0; m2 < 2; ++m2)
        af[m2] = *(const bf16x8*)&As[(w * 32 + m2 * 16 + (l & 15)) * ASTR + ks * 32 + (l >> 4) * 8];
      #pragma unroll
      for (int n2 = 0; n2 < 8; ++n2)
        bfv[n2] = *(const bf16x8*)&Bs[(n2 * 16 + (l & 15)) * ASTR + ks * 32 + (l >> 4) * 8];
      #pragma unroll
      for (int m2 = 0; m2 < 2; ++m2)
        #pragma unroll
        for (int n2 = 0; n2 < 8; ++n2)
          acc[m2][n2] = __builtin_amdgcn_mfma_f32_16x16x32_bf16(af[m2], bfv[n2], acc[m2][n2], 0, 0, 0);
    }

    // Permuted fp8 store: channels n2*16+(l&15) -> bytes (l&15)*8 + n2.
    unsigned char* Yr = Y + ((size_t)r * M + bm) * 128;
    #pragma unroll
    for (int m2 = 0; m2 < 2; ++m2)
      #pragma unroll
      for (int j = 0; j < 4; ++j) {
        int row = w * 32 + m2 * 16 + (l >> 4) * 4 + j;
        if (bm + row < M) {
          int pk0 = __builtin_amdgcn_cvt_pk_fp8_f32(acc[m2][0][j], acc[m2][1][j], 0, false);
          pk0 = __builtin_amdgcn_cvt_pk_fp8_f32(acc[m2][2][j], acc[m2][3][j], pk0, true);
          int pk1 = __builtin_amdgcn_cvt_pk_fp8_f32(acc[m2][4][j], acc[m2][5][j], 0, false);
          pk1 = __builtin_amdgcn_cvt_pk_fp8_f32(acc[m2][6][j], acc[m2][7][j], pk1, true);
          *(int2*)(Yr + (size_t)row * 128 + (l & 15) * 8) = make_int2(pk0, pk1);
        }
      }
  }
}

// ------------------- softmax + gather aggregate (fp8 value path) -------------

__global__ __launch_bounds__(256) void k_aggY(const int* __restrict__ row_ptr, const int* __restrict__ recs,
                                              const float* __restrict__ qkv, const unsigned char* __restrict__ Y,
                                              const float* __restrict__ bias, __bf16* __restrict__ hout,
                                              int N) {
  int wv = threadIdx.x >> 6;
  int lane = threadIdx.x & 63;
  int n = blockIdx.x * 4 + wv;
  if (n >= N) return;
  int start = row_ptr[n], end = row_ptr[n + 1];
  const float* qvn = qkv + (size_t)n * 16;
  float denom = 0.f, m_run = -1e30f;
  int sub = lane & 15;
  int grp = lane >> 4;
  float acc[8];
  #pragma unroll
  for (int j = 0; j < 8; ++j) acc[j] = 0.f;

  for (int c0 = start; c0 < end; c0 += 64) {
    int cend = (end < c0 + 64) ? end : (c0 + 64);
    int cnt = cend - c0;
    int p = c0 + lane;
    float a = -1e30f; int rec = 0;
    if (p < cend) {
      rec = recs[p];
      int s = rec & 0x1FFFF, r = (rec >> 17) & 7;
      float t = qvn[r] + qkv[(size_t)s * 16 + 8 + r];
      a = (t >= 0.f) ? t : 0.2f * t;
    }
    float cm = a;
    #pragma unroll
    for (int off = 32; off; off >>= 1) cm = fmaxf(cm, __shfl_xor(cm, off, 64));
    if (cm > m_run) {
      if (m_run > -1e29f) {
        float scale = __expf(m_run - cm);
        denom *= scale;
        #pragma unroll
        for (int j = 0; j < 8; ++j) acc[j] *= scale;
      }
      m_run = cm;
    }
    float wgt = (p < cend) ? __expf(a - m_run) : 0.f;
    float ws = wgt;
    #pragma unroll
    for (int off = 32; off; off >>= 1) ws += __shfl_xor(ws, off, 64);
    denom += ws;
    int wbits = __float_as_int(wgt);

    int nbatch = (cnt + 3) >> 2;
    #pragma unroll 2
    for (int b = 0; b < nbatch; ++b) {
      int idx = grp * 4 + b * 16;
      int rg = __builtin_amdgcn_ds_bpermute(idx, rec);
      int wg = __builtin_amdgcn_ds_bpermute(idx, wbits);
      float fw = __int_as_float(wg);
      int s_ = rg & 0x1FFFF;
      int r_ = (rg >> 17) & 7;
      int2 xv = *(const int2*)(Y + (((size_t)r_ * N + s_) << 7) + sub * 8);
      f32x2 f01 = __builtin_amdgcn_cvt_pk_f32_fp8(xv.x, false);
      f32x2 f23 = __builtin_amdgcn_cvt_pk_f32_fp8(xv.x, true);
      f32x2 f45 = __builtin_amdgcn_cvt_pk_f32_fp8(xv.y, false);
      f32x2 f67 = __builtin_amdgcn_cvt_pk_f32_fp8(xv.y, true);
      acc[0] += fw * f01[0]; acc[1] += fw * f01[1];
      acc[2] += fw * f23[0]; acc[3] += fw * f23[1];
      acc[4] += fw * f45[0]; acc[5] += fw * f45[1];
      acc[6] += fw * f67[0]; acc[7] += fw * f67[1];
    }
  }

  #pragma unroll
  for (int j = 0; j < 8; ++j) {
    acc[j] += __shfl_xor(acc[j], 16, 64);
    acc[j] += __shfl_xor(acc[j], 32, 64);
  }
  float inv = 1.f / (denom + 1e-16f);
  if (grp == 0) {
    // acc[j] is channel j*16+sub
    #pragma unroll
    for (int j = 0; j < 8; ++j) {
      float v = fmaxf(acc[j] * inv + bias[j * 16 + sub], 0.f);
      hout[(size_t)n * 128 + j * 16 + sub] = (__bf16)v;
    }
  }
}

// ------------------------------- pool + head ---------------------------------

__global__ __launch_bounds__(256) void k_pool(const __bf16* __restrict__ h, float* __restrict__ gsum,
                                              float* __restrict__ gmax, int N) {
  int c2 = threadIdx.x & 63;
  int grp = threadIdx.x >> 6;
  float s0 = 0.f, s1 = 0.f, m0 = 0.f, m1 = 0.f;
  for (int n = blockIdx.x * 4 + grp; n < N; n += gridDim.x * 4) {
    bf16x2 v = ((const bf16x2*)(h + (size_t)n * 128))[c2];
    float v0 = (float)v.x, v1 = (float)v.y;
    s0 += v0; s1 += v1;
    m0 = fmaxf(m0, v0); m1 = fmaxf(m1, v1);
  }
  __shared__ float ss0[256], ss1[256], sm0[256], sm1[256];
  ss0[threadIdx.x] = s0; ss1[threadIdx.x] = s1;
  sm0[threadIdx.x] = m0; sm1[threadIdx.x] = m1;
  __syncthreads();
  if (grp == 0) {
    #pragma unroll
    for (int g = 1; g < 4; ++g) {
      s0 += ss0[g * 64 + c2]; s1 += ss1[g * 64 + c2];
      m0 = fmaxf(m0, sm0[g * 64 + c2]); m1 = fmaxf(m1, sm1[g * 64 + c2]);
    }
    atomicAdd(&gsum[2 * c2 + 0], s0);
    atomicAdd(&gsum[2 * c2 + 1], s1);
    atomicMax((int*)gmax + 2 * c2 + 0, __float_as_int(m0));
    atomicMax((int*)gmax + 2 * c2 + 1, __float_as_int(m1));
  }
}

__global__ void k_head(const float* __restrict__ gsum, const float* __restrict__ gmax,
                       const float* __restrict__ fc1w, const float* __restrict__ fc1b,
                       const float* __restrict__ fc2w, const float* __restrict__ fc2b,
                       float* __restrict__ out, int N) {
  __shared__ float g[256];
  __shared__ float red[128];
  int t = threadIdx.x;
  if (t < 128) g[t] = tanhf(gsum[t] / (float)N);
  else g[t] = tanhf(gmax[t - 128]);
  __syncthreads();
  float r1 = 0.f;
  if (t < 128) {
    float a = fc1b[t];
    for (int i = 0; i < 256; i++) a += g[i] * fc1w[i * 128 + t];
    r1 = a > 0.f ? a : 0.f;
    red[t] = r1 * fc2w[t];
  }
  __syncthreads();
  for (int s = 64; s > 0; s >>= 1) {
    if (t < s) red[t] += red[t + s];
    __syncthreads();
  }
  if (t == 0) {
    float o = red[0] + fc2b[0];
    out[0] = 1.f / (1.f + __expf(-o));
  }
}

// --------------------------------- launch ------------------------------------

extern "C" void kernel_launch(void* const* d_in, const int* in_sizes, int n_in,
                              void* d_out, int out_size, void* d_ws, size_t ws_size,
                              hipStream_t stream) {
  const float* x    = (const float*)d_in[0];
  const int*   ei   = (const int*)d_in[1];
  const int*   ety  = (const int*)d_in[2];
  const float* w0   = (const float*)d_in[3];
  const float* q0   = (const float*)d_in[4];
  const float* k0   = (const float*)d_in[5];
  const float* b0   = (const float*)d_in[6];
  const float* w1   = (const float*)d_in[7];
  const float* q1   = (const float*)d_in[8];
  const float* k1   = (const float*)d_in[9];
  const float* b1   = (const float*)d_in[10];
  const float* fc1w = (const float*)d_in[11];
  const float* fc1b = (const float*)d_in[12];
  const float* fc2w = (const float*)d_in[13];
  const float* fc2b = (const float*)d_in[14];
  int N = in_sizes[0] / 128;
  int E = in_sizes[2];
  const int* src = ei;
  const int* dst = ei + E;

  char* base = (char*)d_ws;
  size_t off = 0;
  auto alloc = [&](size_t bytes) -> void* {
    off = (off + 255) & ~(size_t)255;
    void* p = base + off;
    off += bytes;
    return p;
  };
  int ncb = (N + (1 << CBSH) - 1) >> CBSH;

  int*    row_ptr = (int*)alloc((size_t)(N + 1) * 4);
  int*    ctrl    = (int*)alloc(384 * 4);
  int*    chist   = ctrl;
  int*    ccur0   = ctrl + 64;
  float*  gpool   = (float*)(ctrl + 128);
  float*  gsum    = gpool;
  float*  gmax    = gpool + 128;
  int*    tmp     = (int*)alloc((size_t)E * 4);
  int*    recs    = (int*)alloc((size_t)E * 4);
  float*  qkv     = (float*)alloc((size_t)N * 16 * 4);
  __bf16* wqkb    = (__bf16*)alloc(2 * 2048 * 2);
  __bf16* h1b     = (__bf16*)alloc((size_t)N * 128 * 2);
  __bf16* h2b     = (__bf16*)alloc((size_t)N * 128 * 2);
  __bf16* WT2     = (__bf16*)alloc((size_t)2 * 131072 * 2);
  unsigned char* Y = (unsigned char*)alloc((size_t)8 * N * 128);

  k_zero<<<1, 384, 0, stream>>>(ctrl, 384);
  k_chist<<<256, 256, 0, stream>>>(dst, chist, E);
  k_cscatter<<<(E + CSC_CH - 1) / CSC_CH, 256, 0, stream>>>(src, dst, ety, chist, ccur0, tmp, E);
  k_fsort<<<ncb, 1024, 0, stream>>>(chist, tmp, recs, row_ptr, N, E);

  k_wprep<<<768, 256, 0, stream>>>(w0, q0, k0, w1, q1, k1, wqkb, WT2);

  for (int layer = 0; layer < 2; ++layer) {
    const float* bb   = layer ? b1 : b0;
    __bf16*      hout = layer ? h2b : h1b;
    if (layer == 0)
      k_gemmY<1><<<(N + 127) / 128, 256, 0, stream>>>((const void*)x, WT2, wqkb, Y, qkv, N);
    else
      k_gemmY<0><<<(N + 127) / 128, 256, 0, stream>>>((const void*)h1b, WT2 + 131072, wqkb + 2048, Y, qkv, N);
    k_aggY<<<(N + 3) / 4, 256, 0, stream>>>(row_ptr, recs, qkv, Y, bb, hout, N);
  }

  k_pool<<<256, 256, 0, stream>>>(h2b, gsum, gmax, N);
  k_head<<<1, 256, 0, stream>>>(gsum, gmax, fc1w, fc1b, fc2w, fc2b, (float*)d_out, N);
}